// Round 5
// baseline (1127.611 us; speedup 1.0000x reference)
//
#include <hip/hip_runtime.h>
#include <stdint.h>

#define F0    2048      // base input features (= GEMM K)
#define EROWS 512       // embed rows per level
#define NOUT  2048      // output features (= GEMM N)
#define MROWS 8192      // batch (= GEMM M)
#define PREPB 1024      // prep grid: 4 blocks/CU on 256 CUs -> safely co-resident

typedef __attribute__((ext_vector_type(8))) short bf16x8;
typedef __attribute__((ext_vector_type(4))) float f32x4;
typedef __attribute__((ext_vector_type(8))) unsigned short u16x8;

typedef const __attribute__((address_space(1))) unsigned char ga_t;
typedef __attribute__((address_space(3))) unsigned char lds_t;

__device__ __forceinline__ void async_load16(const void* g, void* l) {
  __builtin_amdgcn_global_load_lds((ga_t*)g, (lds_t*)l, 16, 0, 0);
}

__device__ __forceinline__ unsigned short f2bf(float f) {
  unsigned int u = __builtin_bit_cast(unsigned int, f);
  u += 0x7fffu + ((u >> 16) & 1u);   // round-to-nearest-even
  return (unsigned short)(u >> 16);
}

// Device-scope grid barrier (monotonic counter zeroed by a memset node).
// All PREPB blocks are co-resident: 4 blocks/CU by __launch_bounds__(256,4),
// LDS 9.2KB (17/CU), VGPR capped at 128.
__device__ __forceinline__ void gbar(int* cnt, int target) {
  __syncthreads();
  if (threadIdx.x == 0) {
    __threadfence();
    __hip_atomic_fetch_add(cnt, 1, __ATOMIC_ACQ_REL, __HIP_MEMORY_SCOPE_AGENT);
    while (__hip_atomic_load(cnt, __ATOMIC_ACQUIRE, __HIP_MEMORY_SCOPE_AGENT) < target)
      __builtin_amdgcn_s_sleep(2);
    __threadfence();
  }
  __syncthreads();
}

// ---------------------------------------------------------------------------
// CSR-ize one COO weight: vectorized histogram (8 entries/thread/round),
// parallel Hillis-Steele scan, vectorized scatter.
// ---------------------------------------------------------------------------
__device__ __forceinline__ void csr_build(
    const int* __restrict__ rows, const int* __restrict__ cols,
    const float* __restrict__ vals, int nnz, int nrows,
    int* __restrict__ rp, int* __restrict__ cc, float* __restrict__ cv,
    int* hist, int* tsum)
{
  const int tid = threadIdx.x;
  for (int i = tid; i < nrows; i += 256) hist[i] = 0;
  __syncthreads();

  int k0 = 0;
  for (; k0 + 2048 <= nnz; k0 += 2048) {
    const int kk = k0 + tid * 8;
    int4 ra = *(const int4*)(rows + kk);
    int4 rb = *(const int4*)(rows + kk + 4);
    atomicAdd(&hist[ra.x], 1); atomicAdd(&hist[ra.y], 1);
    atomicAdd(&hist[ra.z], 1); atomicAdd(&hist[ra.w], 1);
    atomicAdd(&hist[rb.x], 1); atomicAdd(&hist[rb.y], 1);
    atomicAdd(&hist[rb.z], 1); atomicAdd(&hist[rb.w], 1);
  }
  for (int k = k0 + tid; k < nnz; k += 256) atomicAdd(&hist[rows[k]], 1);
  __syncthreads();

  const int per = nrows >> 8;            // 2 or 8
  const int base = tid * per;
  int sum = 0;
  for (int i = 0; i < per; ++i) sum += hist[base + i];
  tsum[tid] = sum;
  __syncthreads();
  for (int off = 1; off < 256; off <<= 1) {
    int add = (tid >= off) ? tsum[tid - off] : 0;
    __syncthreads();
    tsum[tid] += add;
    __syncthreads();
  }
  int run = (tid == 0) ? 0 : tsum[tid - 1];
  for (int i = 0; i < per; ++i) { int h = hist[base + i]; hist[base + i] = run; run += h; }
  __syncthreads();

  for (int i = tid; i < nrows; i += 256) rp[i] = hist[i];
  if (tid == 0) rp[nrows] = nnz;
  __syncthreads();

  k0 = 0;
  for (; k0 + 2048 <= nnz; k0 += 2048) {
    const int kk = k0 + tid * 8;
    int4   ra = *(const int4*)(rows + kk);
    int4   rb = *(const int4*)(rows + kk + 4);
    int4   ca = *(const int4*)(cols + kk);
    int4   cb = *(const int4*)(cols + kk + 4);
    float4 va = *(const float4*)(vals + kk);
    float4 vb = *(const float4*)(vals + kk + 4);
    int p;
    p = atomicAdd(&hist[ra.x], 1); cc[p] = ca.x; cv[p] = va.x;
    p = atomicAdd(&hist[ra.y], 1); cc[p] = ca.y; cv[p] = va.y;
    p = atomicAdd(&hist[ra.z], 1); cc[p] = ca.z; cv[p] = va.z;
    p = atomicAdd(&hist[ra.w], 1); cc[p] = ca.w; cv[p] = va.w;
    p = atomicAdd(&hist[rb.x], 1); cc[p] = cb.x; cv[p] = vb.x;
    p = atomicAdd(&hist[rb.y], 1); cc[p] = cb.y; cv[p] = vb.y;
    p = atomicAdd(&hist[rb.z], 1); cc[p] = cb.z; cv[p] = vb.z;
    p = atomicAdd(&hist[rb.w], 1); cc[p] = cb.w; cv[p] = vb.w;
  }
  for (int k = k0 + tid; k < nnz; k += 256) {
    int p = atomicAdd(&hist[rows[k]], 1);
    cc[p] = cols[k]; cv[p] = vals[k];
  }
}

// ---------------------------------------------------------------------------
// Expand one CSR row into a dense x-space row. Direct entries -> LDS atomics;
// indirect -> register AXPY of prior dense row. Thread owns 8 consecutive cols.
// ---------------------------------------------------------------------------
template <bool BF16OUT>
__device__ __forceinline__ void expand_row(
    const int* __restrict__ rp, const int* __restrict__ cc,
    const float* __restrict__ cv, const float* __restrict__ Dsrc, int r,
    void* __restrict__ out,
    float* acc, int* icol, float* ival, int* icnt)
{
  const int tid = threadIdx.x;
  float4* a4 = (float4*)acc;
  a4[tid * 2]     = (float4){0.f, 0.f, 0.f, 0.f};
  a4[tid * 2 + 1] = (float4){0.f, 0.f, 0.f, 0.f};
  if (tid == 0) *icnt = 0;
  __syncthreads();

  const int s = rp[r], e = rp[r + 1];
  for (int i = s + tid; i < e; i += 256) {
    int c = cc[i]; float v = cv[i];
    if (c < F0) atomicAdd(&acc[c], v);
    else { int p = atomicAdd(icnt, 1); if (p < 128) { icol[p] = c - F0; ival[p] = v; } }
  }
  __syncthreads();
  int n = *icnt; if (n > 128) n = 128;

  float4 q0 = a4[tid * 2], q1 = a4[tid * 2 + 1];
  for (int j = 0; j < n; ++j) {
    const float4* src = (const float4*)(Dsrc + (size_t)icol[j] * F0) + tid * 2;
    float v = ival[j];
    float4 s0 = src[0], s1 = src[1];
    q0.x += v * s0.x; q0.y += v * s0.y; q0.z += v * s0.z; q0.w += v * s0.w;
    q1.x += v * s1.x; q1.y += v * s1.y; q1.z += v * s1.z; q1.w += v * s1.w;
  }
  __syncthreads();   // done with acc/icol before caller reuses LDS

  if (BF16OUT) {
    u16x8 o;
    o[0] = f2bf(q0.x); o[1] = f2bf(q0.y); o[2] = f2bf(q0.z); o[3] = f2bf(q0.w);
    o[4] = f2bf(q1.x); o[5] = f2bf(q1.y); o[6] = f2bf(q1.z); o[7] = f2bf(q1.w);
    ((u16x8*)out)[(size_t)r * 256 + tid] = o;
  } else {
    float4* dst = (float4*)out + (size_t)r * 512 + tid * 2;
    dst[0] = q0; dst[1] = q1;
  }
}

// ---------------------------------------------------------------------------
// Fused prep (single node):
//  A: blocks 0..3 CSR-ize the 4 weights; blocks 4..1023 cast x -> bf16
//  B1..B3: blocks 0..511 expand embed level -> D      (barrier between)
//  C: all blocks expand 2 MAIN rows each -> Mb (bf16)
// ---------------------------------------------------------------------------
__global__ __launch_bounds__(256, 4) void prep_kernel(
    const int* __restrict__ r0, const int* __restrict__ c0, const float* __restrict__ v0, int n0,
    const int* __restrict__ r1, const int* __restrict__ c1, const float* __restrict__ v1, int n1,
    const int* __restrict__ r2, const int* __restrict__ c2, const float* __restrict__ v2, int n2,
    const int* __restrict__ rm, const int* __restrict__ cm, const float* __restrict__ vm, int nm,
    int* __restrict__ rp_all, int* __restrict__ cc_all, float* __restrict__ cv_all,
    const float* __restrict__ x, unsigned short* __restrict__ Ab,
    float* __restrict__ D, unsigned short* __restrict__ Mb, int* __restrict__ bar)
{
  const int b = blockIdx.x;
  const int tid = threadIdx.x;

  // LDS union: CSR view {hist[2049], tsum[256]} / expand view
  // {acc[2048], icol[128], ival[128], icnt} -- both 9220 B.
  __shared__ __align__(16) char smem[9232];
  int*   hist = (int*)smem;
  int*   tsum = (int*)(smem + (NOUT + 1) * 4);
  float* acc  = (float*)smem;
  int*   icol = (int*)(smem + F0 * 4);
  float* ival = (float*)(smem + F0 * 4 + 512);
  int*   icnt = (int*)(smem + F0 * 4 + 1024);

  // ---- Phase A
  if (b < 4) {
    const int* rows; const int* cols; const float* vals; int nnz, nrows;
    if      (b == 0) { rows = r0; cols = c0; vals = v0; nnz = n0; nrows = EROWS; }
    else if (b == 1) { rows = r1; cols = c1; vals = v1; nnz = n1; nrows = EROWS; }
    else if (b == 2) { rows = r2; cols = c2; vals = v2; nnz = n2; nrows = EROWS; }
    else             { rows = rm; cols = cm; vals = vm; nnz = nm; nrows = NOUT; }
    csr_build(rows, cols, vals, nnz, nrows,
              rp_all + b * 4096, cc_all + b * 8192, cv_all + b * 8192,
              hist, tsum);
  } else {
    // x cast: 2,097,152 vec8 over 1020 blocks, grid-stride, coalesced
    const float4* xp = (const float4*)x;
    u16x8* ap = (u16x8*)Ab;
    for (int i = (b - 4) * 256 + tid; i < (MROWS * F0) / 8; i += 1020 * 256) {
      float4 a = xp[2 * i], c = xp[2 * i + 1];
      u16x8 o;
      o[0] = f2bf(a.x); o[1] = f2bf(a.y); o[2] = f2bf(a.z); o[3] = f2bf(a.w);
      o[4] = f2bf(c.x); o[5] = f2bf(c.y); o[6] = f2bf(c.z); o[7] = f2bf(c.w);
      ap[i] = o;
    }
  }
  gbar(bar, PREPB);

  // ---- Phase B: embed levels (512 rows each)
  if (b < EROWS)
    expand_row<false>(rp_all + 0 * 4096, cc_all + 0 * 8192, cv_all + 0 * 8192,
                      D, b, (void*)D, acc, icol, ival, icnt);
  gbar(bar, PREPB * 2);
  if (b < EROWS)
    expand_row<false>(rp_all + 1 * 4096, cc_all + 1 * 8192, cv_all + 1 * 8192,
                      D, b, (void*)(D + (size_t)EROWS * F0), acc, icol, ival, icnt);
  gbar(bar, PREPB * 3);
  if (b < EROWS)
    expand_row<false>(rp_all + 2 * 4096, cc_all + 2 * 8192, cv_all + 2 * 8192,
                      D, b, (void*)(D + (size_t)2 * EROWS * F0), acc, icol, ival, icnt);
  gbar(bar, PREPB * 4);

  // ---- Phase C: MAIN rows b and b+1024, straight to bf16
  expand_row<true>(rp_all + 3 * 4096, cc_all + 3 * 8192, cv_all + 3 * 8192,
                   D, b, (void*)Mb, acc, icol, ival, icnt);
  expand_row<true>(rp_all + 3 * 4096, cc_all + 3 * 8192, cv_all + 3 * 8192,
                   D, b + PREPB, (void*)Mb, acc, icol, ival, icnt);
}

// ---------------------------------------------------------------------------
// C[m,n] = sum_k A[m,k] * B[n,k]   (A: MROWSxK bf16, B: NOUTxK bf16, C fp32)
// 128x128 tile, BK=64, 4 waves (2x2 of 64x64), global_load_lds width=16,
// XOR-swizzled LDS.
// ---------------------------------------------------------------------------
__global__ __launch_bounds__(256) void gemm_bt_kernel(
    const unsigned short* __restrict__ A, const unsigned short* __restrict__ B,
    float* __restrict__ C)
{
  constexpr int K = F0;
  constexpr int N = NOUT;
  __shared__ __align__(16) unsigned short sA[128 * 64];
  __shared__ __align__(16) unsigned short sB[128 * 64];

  const int tid  = threadIdx.x;
  const int lane = tid & 63;
  const int w    = tid >> 6;
  const int wm   = (w & 1) * 64;
  const int wn   = (w >> 1) * 64;
  const int mm   = lane & 15;
  const int g    = lane >> 4;
  const int bm   = blockIdx.y;
  const int bn   = blockIdx.x;

  const unsigned short* Ag = A + (size_t)bm * 128 * K;
  const unsigned short* Bg = B + (size_t)bn * 128 * K;

  int su[4], srow[4], scg[4];
  for (int i = 0; i < 4; ++i) {
    int u = i * 256 + tid;
    su[i]   = u;
    srow[i] = u >> 3;
    scg[i]  = (u & 7) ^ ((u >> 3) & 7);
  }

  f32x4 acc[4][4];
  for (int a = 0; a < 4; ++a)
    for (int b2 = 0; b2 < 4; ++b2) acc[a][b2] = (f32x4)0.f;

  for (int k0 = 0; k0 < K; k0 += 64) {
    for (int i = 0; i < 4; ++i) {
      async_load16(Ag + (size_t)srow[i] * K + k0 + scg[i] * 8, sA + su[i] * 8);
      async_load16(Bg + (size_t)srow[i] * K + k0 + scg[i] * 8, sB + su[i] * 8);
    }
    __syncthreads();

    for (int ks = 0; ks < 2; ++ks) {
      bf16x8 af[4], bf[4];
      for (int t = 0; t < 4; ++t) {
        int mrow = wm + t * 16 + mm;
        int sa   = (ks * 4 + g) ^ (mrow & 7);
        af[t] = *(const bf16x8*)(sA + mrow * 64 + sa * 8);
        int nrow = wn + t * 16 + mm;
        int sb   = (ks * 4 + g) ^ (nrow & 7);
        bf[t] = *(const bf16x8*)(sB + nrow * 64 + sb * 8);
      }
      for (int tm = 0; tm < 4; ++tm)
        for (int tn = 0; tn < 4; ++tn)
          acc[tm][tn] = __builtin_amdgcn_mfma_f32_16x16x32_bf16(
              af[tm], bf[tn], acc[tm][tn], 0, 0, 0);
    }
    __syncthreads();
  }

  for (int tm = 0; tm < 4; ++tm) {
    int rowb = bm * 128 + wm + tm * 16 + g * 4;
    for (int tn = 0; tn < 4; ++tn) {
      int col = bn * 128 + wn + tn * 16 + mm;
      for (int r = 0; r < 4; ++r)
        C[(size_t)(rowb + r) * N + col] = acc[tm][tn][r];
    }
  }
}

// ---------------------------------------------------------------------------
extern "C" void kernel_launch(void* const* d_in, const int* in_sizes, int n_in,
                              void* d_out, int out_size, void* d_ws, size_t ws_size,
                              hipStream_t stream)
{
  const float* x   = (const float*)d_in[0];
  const int*   er0 = (const int*)d_in[1];
  const int*   ec0 = (const int*)d_in[2];
  const float* ev0 = (const float*)d_in[3];
  const int*   er1 = (const int*)d_in[4];
  const int*   ec1 = (const int*)d_in[5];
  const float* ev1 = (const float*)d_in[6];
  const int*   er2 = (const int*)d_in[7];
  const int*   ec2 = (const int*)d_in[8];
  const float* ev2 = (const float*)d_in[9];
  const int*   mr  = (const int*)d_in[10];
  const int*   mc  = (const int*)d_in[11];
  const float* mv  = (const float*)d_in[12];
  const int nnz_e0 = in_sizes[1];
  const int nnz_e1 = in_sizes[4];
  const int nnz_e2 = in_sizes[7];
  const int nnz_m  = in_sizes[10];

  // ws: [bar 256B] [rp_all 4x4096 int] [cc_all 48K int] [cv_all 48K f32]
  //     [D 12MB f32] [Mb 8MB bf16] [Ab 32MB bf16]
  int*   bar    = (int*)d_ws;
  int*   rp_all = (int*)((char*)d_ws + 256);
  int*   cc_all = rp_all + 4 * 4096;
  float* cv_all = (float*)(cc_all + 48 * 1024);
  float* D      = (float*)(cv_all + 48 * 1024);
  unsigned short* Mb = (unsigned short*)(D + (size_t)3 * EROWS * F0);
  unsigned short* Ab = Mb + (size_t)NOUT * F0;

  hipMemsetAsync(bar, 0, 4, stream);

  hipLaunchKernelGGL(prep_kernel, dim3(PREPB), dim3(256), 0, stream,
                     er0, ec0, ev0, nnz_e0,
                     er1, ec1, ev1, nnz_e1,
                     er2, ec2, ev2, nnz_e2,
                     mr,  mc,  mv,  nnz_m,
                     rp_all, cc_all, cv_all, x, Ab, D, Mb, bar);

  hipLaunchKernelGGL(gemm_bt_kernel, dim3(NOUT / 128, MROWS / 128), dim3(256),
                     0, stream, Ab, Mb, (float*)d_out);
}